// Round 4
// baseline (7317.040 us; speedup 1.0000x reference)
//
#include <hip/hip_runtime.h>
#include <hip/hip_cooperative_groups.h>

namespace cg = cooperative_groups;

// ---------- types ----------
typedef __attribute__((ext_vector_type(8))) short bf16x8;   // 8 bf16 in 4 VGPRs
typedef __attribute__((ext_vector_type(4))) float f32x4;

// ---------- bf16 helpers (RNE, bit-level) ----------
__device__ __forceinline__ short f2bf(float f) {
    union { float f; unsigned u; } v; v.f = f;
    unsigned r = v.u + 0x7fffu + ((v.u >> 16) & 1u);
    return (short)(r >> 16);
}
__device__ __forceinline__ float bf2f(short s) {
    union { unsigned u; float f; } v; v.u = ((unsigned)(unsigned short)s) << 16;
    return v.f;
}
__device__ __forceinline__ unsigned pack2(float x, float y) {
    return (unsigned)(unsigned short)f2bf(x) | ((unsigned)(unsigned short)f2bf(y) << 16);
}
__device__ __forceinline__ uint4 pack8(float4 a, float4 b) {
    return make_uint4(pack2(a.x, a.y), pack2(a.z, a.w), pack2(b.x, b.y), pack2(b.z, b.w));
}
__device__ __forceinline__ float tanh_fast(float x) {
    float e = __expf(2.f * x);
    return 1.f - 2.f / (e + 1.f);
}

// ---------- prep: fp32 [1024][1024] -> bf16 ----------
__global__ __launch_bounds__(256) void pack_w(const float* __restrict__ src,
                                              short* __restrict__ dst) {
    int idx = (blockIdx.x * 256 + threadIdx.x) * 8;
    float4 f0 = ((const float4*)(src + idx))[0];
    float4 f1 = ((const float4*)(src + idx))[1];
    *(uint4*)(dst + idx) = pack8(f0, f1);
}

__global__ void prep_b(const float* __restrict__ b_ih, const float* __restrict__ b_hh,
                       float* __restrict__ bsum) {
    int n = threadIdx.x;
    bsum[n] = b_ih[n] + b_hh[n];
}

// ---------- xpose: X[t*1024+b][k] = bf16(av[b][t][k]) — coalesced both sides ----------
__global__ __launch_bounds__(256) void xpose(const float* __restrict__ av,
                                             short* __restrict__ X) {
    int gid = blockIdx.x * 256 + threadIdx.x;    // 8,388,608 threads, 8 elems each
    int k8  = gid & 127;                          // k-chunk (8 elems)
    int row = gid >> 7;                           // av row = b*64 + t
    int b = row >> 6, t = row & 63;
    const float* src = av + (size_t)row * 1024 + k8 * 8;
    float4 f0 = ((const float4*)src)[0];
    float4 f1 = ((const float4*)src)[1];
    *(uint4*)(X + ((size_t)((t << 10) | b)) * 1024 + k8 * 8) = pack8(f0, f1);
}

// ---------- zgemm: Z[t*1024+b][n] = bf16(X . Wih^T + bsum) ----------
// M=65536, K=1024, N=1024; 128x128 tile, BK=64, 256 thr (4 waves 2x2, wave 64x64)
// XCD swizzle: supergroup of 64 blocks = 8 m-tiles x 8 n-tiles, m_idx%8 == g%8
#define ZLDK 72   // padded K stride (elems)

__global__ __launch_bounds__(256) void zgemm(const short* __restrict__ X,
                                             const short* __restrict__ Wih,
                                             const float* __restrict__ bsum,
                                             short* __restrict__ Z) {
    __shared__ short smem[2 * 128 * ZLDK];        // As | Bs, reused as Cs in epilogue
    short* As = smem;
    short* Bs = smem + 128 * ZLDK;

    const int tid = threadIdx.x, lane = tid & 63, wave = tid >> 6;
    const int wm = wave >> 1, wn = wave & 1;
    const int gb = blockIdx.x;
    const int sg = gb >> 6, local = gb & 63;
    const int m_idx = sg * 8 + (local & 7);       // 0..511, pinned to XCD local&7
    const int n_idx = local >> 3;                 // 0..7
    const int m0 = m_idx * 128, n0 = n_idx * 128;
    const int srow = tid >> 1, scol = (tid & 1) * 32;   // 2 thr/row, 32 bf16 each

    const short* asrc = X + (size_t)(m0 + srow) * 1024 + scol;
    const short* bsrc = Wih + (size_t)(n0 + srow) * 1024 + scol;

    uint4 ra[4], rb[4];
    #pragma unroll
    for (int j = 0; j < 4; j++) {
        ra[j] = *(const uint4*)(asrc + 8 * j);
        rb[j] = *(const uint4*)(bsrc + 8 * j);
    }

    f32x4 acc[4][4];
    #pragma unroll
    for (int i = 0; i < 4; i++)
        #pragma unroll
        for (int j = 0; j < 4; j++) acc[i][j] = (f32x4)0.0f;

    const int r = lane & 15, q = lane >> 4;
    const int koff = q * 8;

    for (int kt = 0; kt < 16; ++kt) {
        #pragma unroll
        for (int j = 0; j < 4; j++) {
            *(uint4*)&As[srow * ZLDK + scol + 8 * j] = ra[j];
            *(uint4*)&Bs[srow * ZLDK + scol + 8 * j] = rb[j];
        }
        __syncthreads();

        if (kt < 15) {
            int k = (kt + 1) * 64;
            #pragma unroll
            for (int j = 0; j < 4; j++) {
                ra[j] = *(const uint4*)(asrc + k + 8 * j);
                rb[j] = *(const uint4*)(bsrc + k + 8 * j);
            }
        }

        #pragma unroll
        for (int ks = 0; ks < 2; ++ks) {
            bf16x8 af[4], bfr[4];
            #pragma unroll
            for (int i = 0; i < 4; i++) {
                af[i]  = *(const bf16x8*)&As[(wm * 64 + i * 16 + r) * ZLDK + ks * 32 + koff];
                bfr[i] = *(const bf16x8*)&Bs[(wn * 64 + i * 16 + r) * ZLDK + ks * 32 + koff];
            }
            #pragma unroll
            for (int i = 0; i < 4; i++)
                #pragma unroll
                for (int j = 0; j < 4; j++)
                    acc[i][j] = __builtin_amdgcn_mfma_f32_16x16x32_bf16(af[i], bfr[j], acc[i][j], 0, 0, 0);
        }
        __syncthreads();
    }

    // epilogue: acc -> LDS (bf16, stride 136) -> coalesced dwordx4 stores
    #pragma unroll
    for (int j = 0; j < 4; j++) {
        int nl = wn * 64 + j * 16 + r;
        float bs = bsum[n0 + nl];
        #pragma unroll
        for (int i = 0; i < 4; i++) {
            int ml = wm * 64 + i * 16 + q * 4;
            #pragma unroll
            for (int rr = 0; rr < 4; rr++)
                smem[(ml + rr) * 136 + nl] = f2bf(acc[i][j][rr] + bs);
        }
    }
    __syncthreads();
    {
        int row = tid >> 1, cb = (tid & 1) * 64;
        const short* src = smem + row * 136 + cb;
        short* dst = Z + (size_t)(m0 + row) * 1024 + n0 + cb;
        #pragma unroll
        for (int jj = 0; jj < 8; jj++)
            *(uint4*)(dst + 8 * jj) = *(const uint4*)(src + 8 * jj);
    }
}

// ---------- persistent RNN chain: t0 elementwise + 63 GEMM steps, one dispatch ----------
// grid 256 blocks (16x16 tiles of 64x64), 512 thr (8 waves 2x4, wave 32x16), BK=128
// Whh staging values live in 64 VGPRs for the whole kernel (zero global B traffic).
#define SLDK 136

__global__ __launch_bounds__(512) void rnn_persist(const short* __restrict__ Whh,
                                                   const short* __restrict__ Z,
                                                   short* __restrict__ hA,
                                                   short* __restrict__ hB) {
    cg::grid_group grid = cg::this_grid();
    __shared__ short As[64 * SLDK];
    __shared__ short Bs[64 * SLDK];

    const int tid = threadIdx.x, lane = tid & 63, wave = tid >> 6;
    const int wm = wave >> 2, wn = wave & 3;
    const int g = blockIdx.x;
    const int m0 = (g & 15) * 64, n0 = (g >> 4) * 64;   // m pinned to XCD g%8
    const int srow = tid >> 3, scol = (tid & 7) * 16;
    const int r = lane & 15, q = lane >> 4;
    const int arow = wm * 32 + r, brow = wn * 16 + r;
    const int koff = q * 8;

    // preload this block's Whh staging values (fixed n-tile, all K) into registers
    const short* bsrc = Whh + (size_t)(n0 + srow) * 1024 + scol;
    uint4 rbAll[16];
    #pragma unroll
    for (int c = 0; c < 8; ++c) {
        rbAll[c * 2]     = *(const uint4*)(bsrc + c * 128);
        rbAll[c * 2 + 1] = *(const uint4*)(bsrc + c * 128 + 8);
    }

    // t = 0: h1 = tanh(Z[0]) elementwise (1M elems / 256 blocks / 512 thr = 8 each)
    {
        int base = (g * 512 + tid) * 8;
        uint4 zv = *(const uint4*)(Z + base);
        const unsigned* zp = (const unsigned*)&zv;
        uint4 o; unsigned* op = (unsigned*)&o;
        #pragma unroll
        for (int j2 = 0; j2 < 4; j2++) {
            float lo = tanh_fast(bf2f((short)(zp[j2] & 0xffffu)));
            float hi = tanh_fast(bf2f((short)(zp[j2] >> 16)));
            op[j2] = pack2(lo, hi);
        }
        *(uint4*)(hA + base) = o;
    }
    __threadfence();
    grid.sync();

    for (int t = 1; t < 64; ++t) {
        const short* hin = (t & 1) ? hA : hB;
        short* hout      = (t & 1) ? hB : hA;
        const short* asrc = hin + (size_t)(m0 + srow) * 1024 + scol;

        uint4 ra0 = *(const uint4*)asrc;
        uint4 ra1 = *(const uint4*)(asrc + 8);

        f32x4 acc0 = (f32x4)0.0f, acc1 = (f32x4)0.0f;

        #pragma unroll
        for (int chunk = 0; chunk < 8; ++chunk) {
            *(uint4*)&As[srow * SLDK + scol]     = ra0;
            *(uint4*)&As[srow * SLDK + scol + 8] = ra1;
            *(uint4*)&Bs[srow * SLDK + scol]     = rbAll[chunk * 2];
            *(uint4*)&Bs[srow * SLDK + scol + 8] = rbAll[chunk * 2 + 1];
            __syncthreads();

            if (chunk < 7) {
                ra0 = *(const uint4*)(asrc + (chunk + 1) * 128);
                ra1 = *(const uint4*)(asrc + (chunk + 1) * 128 + 8);
            }

            #pragma unroll
            for (int ks = 0; ks < 4; ++ks) {
                bf16x8 a0 = *(const bf16x8*)&As[arow * SLDK + ks * 32 + koff];
                bf16x8 a1 = *(const bf16x8*)&As[(arow + 16) * SLDK + ks * 32 + koff];
                bf16x8 b  = *(const bf16x8*)&Bs[brow * SLDK + ks * 32 + koff];
                acc0 = __builtin_amdgcn_mfma_f32_16x16x32_bf16(a0, b, acc0, 0, 0, 0);
                acc1 = __builtin_amdgcn_mfma_f32_16x16x32_bf16(a1, b, acc1, 0, 0, 0);
            }
            __syncthreads();
        }

        const short* zt = Z + ((size_t)t << 20);
        int n = n0 + wn * 16 + r;
        #pragma unroll
        for (int mi = 0; mi < 2; mi++) {
            int mb = m0 + wm * 32 + mi * 16 + q * 4;
            f32x4 a = mi ? acc1 : acc0;
            #pragma unroll
            for (int rr = 0; rr < 4; rr++) {
                float z = bf2f(zt[((size_t)(mb + rr) << 10) + n]);
                hout[((size_t)(mb + rr) << 10) + n] = f2bf(tanh_fast(a[rr] + z));
            }
        }
        __threadfence();
        grid.sync();
    }
}

// ---------- head: p[b] = sigmoid(h . W_out + b_out), wave-per-row ----------
__global__ __launch_bounds__(256) void head_kernel(const short* __restrict__ h,
                                                   const float* __restrict__ W_out,
                                                   const float* __restrict__ b_out,
                                                   float* __restrict__ p) {
    int b    = blockIdx.x * 4 + (threadIdx.x >> 6);
    int lane = threadIdx.x & 63;
    float s = 0.f;
    for (int k = lane; k < 1024; k += 64)
        s += bf2f(h[(size_t)b * 1024 + k]) * W_out[k];
    #pragma unroll
    for (int off = 32; off > 0; off >>= 1) s += __shfl_down(s, off);
    if (lane == 0) p[b] = 1.f / (1.f + __expf(-(s + b_out[0])));
}

// ---------- loss: BCE mean with torch-style log clamp at -100 ----------
__global__ __launch_bounds__(1024) void loss_kernel(const float* __restrict__ p,
                                                    const float* __restrict__ y,
                                                    float* __restrict__ loss) {
    __shared__ float red[1024];
    int b = threadIdx.x;
    float pv = p[b];
    float yb = (y[b] >= 1e-5f) ? 1.f : 0.f;
    float lp = fmaxf(logf(pv), -100.f);
    float l1 = fmaxf(log1pf(-pv), -100.f);
    red[b] = yb * lp + (1.f - yb) * l1;
    __syncthreads();
    for (int s = 512; s > 0; s >>= 1) {
        if (b < s) red[b] += red[b + s];
        __syncthreads();
    }
    if (b == 0) loss[0] = -red[0] / 1024.f;
}

// ---------- launch ----------
extern "C" void kernel_launch(void* const* d_in, const int* in_sizes, int n_in,
                              void* d_out, int out_size, void* d_ws, size_t ws_size,
                              hipStream_t stream) {
    const float* av    = (const float*)d_in[3];
    const float* y     = (const float*)d_in[4];
    const float* W_ih  = (const float*)d_in[5];
    const float* b_ih  = (const float*)d_in[6];
    const float* W_hh  = (const float*)d_in[7];
    const float* b_hh  = (const float*)d_in[8];
    const float* W_out = (const float*)d_in[9];
    const float* b_out = (const float*)d_in[10];
    float* out = (float*)d_out;                      // [0]=loss, [1..1024]=p

    char* ws = (char*)d_ws;
    short* Wih_bf = (short*)ws;                      // 2 MB
    short* Whh_bf = (short*)(ws + (2ull << 20));     // 2 MB
    float* bsum   = (float*)(ws + (4ull << 20));     // 4 KB
    short* hA     = (short*)(ws + (5ull << 20));     // 2 MB
    short* hB     = (short*)(ws + (7ull << 20));     // 2 MB
    short* X      = (short*)(ws + (16ull << 20));    // 128 MB bf16 [65536][1024]
    short* Z      = (short*)(ws + (160ull << 20));   // 128 MB bf16 [65536][1024]

    pack_w<<<512, 256, 0, stream>>>(W_ih, Wih_bf);
    pack_w<<<512, 256, 0, stream>>>(W_hh, Whh_bf);
    prep_b<<<1, 1024, 0, stream>>>(b_ih, b_hh, bsum);
    xpose<<<32768, 256, 0, stream>>>(av, X);

    zgemm<<<4096, 256, 0, stream>>>(X, Wih_bf, bsum, Z);

    void* args[] = { (void*)&Whh_bf, (void*)&Z, (void*)&hA, (void*)&hB };
    hipLaunchCooperativeKernel((void*)rnn_persist, dim3(256), dim3(512), args, 0, stream);

    // t=63 (odd) wrote hB = h_64
    head_kernel<<<256, 256, 0, stream>>>(hB, W_out, b_out, out + 1);
    loss_kernel<<<1, 1024, 0, stream>>>(out + 1, y, out);
}

// Round 5
// 2525.550 us; speedup vs baseline: 2.8972x; 2.8972x over previous
//
#include <hip/hip_runtime.h>

// ---------- types ----------
typedef __attribute__((ext_vector_type(8))) short bf16x8;   // 8 bf16 in 4 VGPRs
typedef __attribute__((ext_vector_type(4))) float f32x4;

// ---------- bf16 helpers (RNE, bit-level) ----------
__device__ __forceinline__ short f2bf(float f) {
    union { float f; unsigned u; } v; v.f = f;
    unsigned r = v.u + 0x7fffu + ((v.u >> 16) & 1u);
    return (short)(r >> 16);
}
__device__ __forceinline__ float bf2f(short s) {
    union { unsigned u; float f; } v; v.u = ((unsigned)(unsigned short)s) << 16;
    return v.f;
}
__device__ __forceinline__ unsigned pack2(float x, float y) {
    return (unsigned)(unsigned short)f2bf(x) | ((unsigned)(unsigned short)f2bf(y) << 16);
}
__device__ __forceinline__ uint4 pack8(float4 a, float4 b) {
    return make_uint4(pack2(a.x, a.y), pack2(a.z, a.w), pack2(b.x, b.y), pack2(b.z, b.w));
}
__device__ __forceinline__ float tanh_fast(float x) {
    float e = __expf(2.f * x);
    return 1.f - 2.f / (e + 1.f);
}

// ---------- prep: fp32 [1024][1024] -> bf16 ----------
__global__ __launch_bounds__(256) void pack_w(const float* __restrict__ src,
                                              short* __restrict__ dst) {
    int idx = (blockIdx.x * 256 + threadIdx.x) * 8;
    float4 f0 = ((const float4*)(src + idx))[0];
    float4 f1 = ((const float4*)(src + idx))[1];
    *(uint4*)(dst + idx) = pack8(f0, f1);
}

__global__ void prep_b(const float* __restrict__ b_ih, const float* __restrict__ b_hh,
                       float* __restrict__ bsum) {
    int n = threadIdx.x;
    bsum[n] = b_ih[n] + b_hh[n];
}

// ---------- xpose: X[t*1024+b][k] = bf16(av[b][t][k]) — coalesced both sides ----------
__global__ __launch_bounds__(256) void xpose(const float* __restrict__ av,
                                             short* __restrict__ X) {
    int gid = blockIdx.x * 256 + threadIdx.x;    // 8,388,608 threads, 8 elems each
    int k8  = gid & 127;                          // k-chunk (8 elems)
    int row = gid >> 7;                           // av row = b*64 + t
    int b = row >> 6, t = row & 63;
    const float* src = av + (size_t)row * 1024 + k8 * 8;
    float4 f0 = ((const float4*)src)[0];
    float4 f1 = ((const float4*)src)[1];
    *(uint4*)(X + ((size_t)((t << 10) | b)) * 1024 + k8 * 8) = pack8(f0, f1);
}

// ---------- zgemm: Z[t*1024+b][n] = bf16(X . Wih^T + bsum) ----------
// M=65536, K=1024, N=1024; 128x128 tile, BK=64, 256 thr (4 waves 2x2, wave 64x64)
// XCD swizzle: supergroup of 64 blocks = 8 m-tiles x 8 n-tiles, m_idx%8 == g%8
#define ZLDK 72   // padded K stride (elems)

__global__ __launch_bounds__(256) void zgemm(const short* __restrict__ X,
                                             const short* __restrict__ Wih,
                                             const float* __restrict__ bsum,
                                             short* __restrict__ Z) {
    __shared__ short smem[2 * 128 * ZLDK];        // As | Bs, reused as Cs in epilogue
    short* As = smem;
    short* Bs = smem + 128 * ZLDK;

    const int tid = threadIdx.x, lane = tid & 63, wave = tid >> 6;
    const int wm = wave >> 1, wn = wave & 1;
    const int gb = blockIdx.x;
    const int sg = gb >> 6, local = gb & 63;
    const int m_idx = sg * 8 + (local & 7);       // 0..511, pinned to XCD local&7
    const int n_idx = local >> 3;                 // 0..7
    const int m0 = m_idx * 128, n0 = n_idx * 128;
    const int srow = tid >> 1, scol = (tid & 1) * 32;   // 2 thr/row, 32 bf16 each

    const short* asrc = X + (size_t)(m0 + srow) * 1024 + scol;
    const short* bsrc = Wih + (size_t)(n0 + srow) * 1024 + scol;

    uint4 ra[4], rb[4];
    #pragma unroll
    for (int j = 0; j < 4; j++) {
        ra[j] = *(const uint4*)(asrc + 8 * j);
        rb[j] = *(const uint4*)(bsrc + 8 * j);
    }

    f32x4 acc[4][4];
    #pragma unroll
    for (int i = 0; i < 4; i++)
        #pragma unroll
        for (int j = 0; j < 4; j++) acc[i][j] = (f32x4)0.0f;

    const int r = lane & 15, q = lane >> 4;
    const int koff = q * 8;

    for (int kt = 0; kt < 16; ++kt) {
        #pragma unroll
        for (int j = 0; j < 4; j++) {
            *(uint4*)&As[srow * ZLDK + scol + 8 * j] = ra[j];
            *(uint4*)&Bs[srow * ZLDK + scol + 8 * j] = rb[j];
        }
        __syncthreads();

        if (kt < 15) {
            int k = (kt + 1) * 64;
            #pragma unroll
            for (int j = 0; j < 4; j++) {
                ra[j] = *(const uint4*)(asrc + k + 8 * j);
                rb[j] = *(const uint4*)(bsrc + k + 8 * j);
            }
        }

        #pragma unroll
        for (int ks = 0; ks < 2; ++ks) {
            bf16x8 af[4], bfr[4];
            #pragma unroll
            for (int i = 0; i < 4; i++) {
                af[i]  = *(const bf16x8*)&As[(wm * 64 + i * 16 + r) * ZLDK + ks * 32 + koff];
                bfr[i] = *(const bf16x8*)&Bs[(wn * 64 + i * 16 + r) * ZLDK + ks * 32 + koff];
            }
            #pragma unroll
            for (int i = 0; i < 4; i++)
                #pragma unroll
                for (int j = 0; j < 4; j++)
                    acc[i][j] = __builtin_amdgcn_mfma_f32_16x16x32_bf16(af[i], bfr[j], acc[i][j], 0, 0, 0);
        }
        __syncthreads();
    }

    // epilogue: acc -> LDS (bf16, stride 136) -> coalesced dwordx4 stores
    #pragma unroll
    for (int j = 0; j < 4; j++) {
        int nl = wn * 64 + j * 16 + r;
        float bs = bsum[n0 + nl];
        #pragma unroll
        for (int i = 0; i < 4; i++) {
            int ml = wm * 64 + i * 16 + q * 4;
            #pragma unroll
            for (int rr = 0; rr < 4; rr++)
                smem[(ml + rr) * 136 + nl] = f2bf(acc[i][j][rr] + bs);
        }
    }
    __syncthreads();
    {
        int row = tid >> 1, cb = (tid & 1) * 64;
        const short* src = smem + row * 136 + cb;
        short* dst = Z + (size_t)(m0 + row) * 1024 + n0 + cb;
        #pragma unroll
        for (int jj = 0; jj < 8; jj++)
            *(uint4*)(dst + 8 * jj) = *(const uint4*)(src + 8 * jj);
    }
}

// ---------- t=0: h1 = tanh(Z[0]) elementwise ----------
__global__ __launch_bounds__(256) void t0_kernel(const short* __restrict__ Z,
                                                 short* __restrict__ h) {
    int idx = (blockIdx.x * 256 + threadIdx.x) * 8;
    uint4 zv = *(const uint4*)(Z + idx);
    const unsigned* zp = (const unsigned*)&zv;
    uint4 out;
    unsigned* op = (unsigned*)&out;
    #pragma unroll
    for (int j = 0; j < 4; j++) {
        float lo = tanh_fast(bf2f((short)(zp[j] & 0xffffu)));
        float hi = tanh_fast(bf2f((short)(zp[j] >> 16)));
        op[j] = pack2(lo, hi);
    }
    *(uint4*)(h + idx) = out;
}

// ---------- RNN step t>=1: h' = tanh(h . W_hh^T + Z[t]) ----------
// 32x64 tile, grid (16 n, 32 m) = 512 blocks, 256 thr (4 waves 2x2, wave 16x32),
// BK=128 reg-prefetch. 2 blocks/CU (launch_bounds min 2 waves/EU) so one block's
// barrier stalls are hidden by the co-resident block's waves.
#define SLDK 136  // padded K stride: 272B = 68 dwords == 4 mod 32 -> 2-way reads (free)

__global__ __launch_bounds__(256, 2) void step_kernel(const short* __restrict__ Whh,
                                                      const short* __restrict__ Z,
                                                      const short* __restrict__ h_in,
                                                      short* __restrict__ h_out, int t) {
    __shared__ short As[32 * SLDK];
    __shared__ short Bs[64 * SLDK];

    const int tid = threadIdx.x, lane = tid & 63, wave = tid >> 6;
    const int wm = wave >> 1, wn = wave & 1;
    const int m0 = blockIdx.y * 32, n0 = blockIdx.x * 64;

    // A staging: 32 rows, 8 thr/row, 16 elems each
    const int rowA = tid >> 3, colA = (tid & 7) * 16;
    // B staging: 64 rows, 4 thr/row, 32 elems each
    const int rowB = tid >> 2, colB = (tid & 3) * 32;

    const short* asrc = h_in + (size_t)(m0 + rowA) * 1024 + colA;
    const short* bsrc = Whh + (size_t)(n0 + rowB) * 1024 + colB;

    uint4 ra0 = *(const uint4*)asrc;
    uint4 ra1 = *(const uint4*)(asrc + 8);
    uint4 rb[4];
    #pragma unroll
    for (int j = 0; j < 4; j++) rb[j] = *(const uint4*)(bsrc + 8 * j);

    f32x4 acc0 = (f32x4)0.0f, acc1 = (f32x4)0.0f;

    const int r = lane & 15, q = lane >> 4;
    const int arow  = wm * 16 + r;
    const int brow0 = wn * 32 + r;
    const int brow1 = wn * 32 + 16 + r;
    const int koff  = q * 8;

    for (int chunk = 0; chunk < 8; ++chunk) {
        *(uint4*)&As[rowA * SLDK + colA]     = ra0;
        *(uint4*)&As[rowA * SLDK + colA + 8] = ra1;
        #pragma unroll
        for (int j = 0; j < 4; j++)
            *(uint4*)&Bs[rowB * SLDK + colB + 8 * j] = rb[j];
        __syncthreads();

        if (chunk < 7) {
            int k = (chunk + 1) * 128;
            ra0 = *(const uint4*)(asrc + k);
            ra1 = *(const uint4*)(asrc + k + 8);
            #pragma unroll
            for (int j = 0; j < 4; j++) rb[j] = *(const uint4*)(bsrc + k + 8 * j);
        }

        #pragma unroll
        for (int ks = 0; ks < 4; ++ks) {
            bf16x8 a  = *(const bf16x8*)&As[arow * SLDK + ks * 32 + koff];
            bf16x8 b0 = *(const bf16x8*)&Bs[brow0 * SLDK + ks * 32 + koff];
            bf16x8 b1 = *(const bf16x8*)&Bs[brow1 * SLDK + ks * 32 + koff];
            acc0 = __builtin_amdgcn_mfma_f32_16x16x32_bf16(a, b0, acc0, 0, 0, 0);
            acc1 = __builtin_amdgcn_mfma_f32_16x16x32_bf16(a, b1, acc1, 0, 0, 0);
        }
        __syncthreads();
    }

    // epilogue: C layout col = lane&15 (from B frag), row = q*4+rr (from A frag)
    const short* zt = Z + ((size_t)t << 20);
    const int nb0 = n0 + wn * 32 + r;
    const int nb1 = nb0 + 16;
    const int mb  = m0 + wm * 16 + q * 4;
    #pragma unroll
    for (int rr = 0; rr < 4; rr++) {
        size_t rowoff = (size_t)(mb + rr) << 10;
        float z0 = bf2f(zt[rowoff + nb0]);
        float z1 = bf2f(zt[rowoff + nb1]);
        h_out[rowoff + nb0] = f2bf(tanh_fast(acc0[rr] + z0));
        h_out[rowoff + nb1] = f2bf(tanh_fast(acc1[rr] + z1));
    }
}

// ---------- head: p[b] = sigmoid(h . W_out + b_out), wave-per-row ----------
__global__ __launch_bounds__(256) void head_kernel(const short* __restrict__ h,
                                                   const float* __restrict__ W_out,
                                                   const float* __restrict__ b_out,
                                                   float* __restrict__ p) {
    int b    = blockIdx.x * 4 + (threadIdx.x >> 6);
    int lane = threadIdx.x & 63;
    float s = 0.f;
    for (int k = lane; k < 1024; k += 64)
        s += bf2f(h[(size_t)b * 1024 + k]) * W_out[k];
    #pragma unroll
    for (int off = 32; off > 0; off >>= 1) s += __shfl_down(s, off);
    if (lane == 0) p[b] = 1.f / (1.f + __expf(-(s + b_out[0])));
}

// ---------- loss: BCE mean with torch-style log clamp at -100 ----------
__global__ __launch_bounds__(1024) void loss_kernel(const float* __restrict__ p,
                                                    const float* __restrict__ y,
                                                    float* __restrict__ loss) {
    __shared__ float red[1024];
    int b = threadIdx.x;
    float pv = p[b];
    float yb = (y[b] >= 1e-5f) ? 1.f : 0.f;
    float lp = fmaxf(logf(pv), -100.f);
    float l1 = fmaxf(log1pf(-pv), -100.f);
    red[b] = yb * lp + (1.f - yb) * l1;
    __syncthreads();
    for (int s = 512; s > 0; s >>= 1) {
        if (b < s) red[b] += red[b + s];
        __syncthreads();
    }
    if (b == 0) loss[0] = -red[0] / 1024.f;
}

// ---------- launch ----------
extern "C" void kernel_launch(void* const* d_in, const int* in_sizes, int n_in,
                              void* d_out, int out_size, void* d_ws, size_t ws_size,
                              hipStream_t stream) {
    const float* av    = (const float*)d_in[3];
    const float* y     = (const float*)d_in[4];
    const float* W_ih  = (const float*)d_in[5];
    const float* b_ih  = (const float*)d_in[6];
    const float* W_hh  = (const float*)d_in[7];
    const float* b_hh  = (const float*)d_in[8];
    const float* W_out = (const float*)d_in[9];
    const float* b_out = (const float*)d_in[10];
    float* out = (float*)d_out;                      // [0]=loss, [1..1024]=p

    char* ws = (char*)d_ws;
    short* Wih_bf = (short*)ws;                      // 2 MB
    short* Whh_bf = (short*)(ws + (2ull << 20));     // 2 MB
    float* bsum   = (float*)(ws + (4ull << 20));     // 4 KB
    short* hb0    = (short*)(ws + (5ull << 20));     // 2 MB
    short* hb1    = (short*)(ws + (7ull << 20));     // 2 MB
    short* X      = (short*)(ws + (16ull << 20));    // 128 MB bf16 [65536][1024]
    short* Z      = (short*)(ws + (160ull << 20));   // 128 MB bf16 [65536][1024]

    pack_w<<<512, 256, 0, stream>>>(W_ih, Wih_bf);
    pack_w<<<512, 256, 0, stream>>>(W_hh, Whh_bf);
    prep_b<<<1, 1024, 0, stream>>>(b_ih, b_hh, bsum);
    xpose<<<32768, 256, 0, stream>>>(av, X);

    zgemm<<<4096, 256, 0, stream>>>(X, Wih_bf, bsum, Z);

    short* hbuf[2] = { hb0, hb1 };
    t0_kernel<<<512, 256, 0, stream>>>(Z, hb1);      // h_1 = tanh(Z[0]) -> hbuf[1]
    for (int t = 1; t < 64; ++t) {
        short* hin  = hbuf[t & 1];
        short* hout = hbuf[(t + 1) & 1];
        step_kernel<<<dim3(16, 32), 256, 0, stream>>>(Whh_bf, Z, hin, hout, t);
    }
    // t=63 writes hbuf[0]
    head_kernel<<<256, 256, 0, stream>>>(hb0, W_out, b_out, out + 1);
    loss_kernel<<<1, 1024, 0, stream>>>(out + 1, y, out);
}